// Round 2
// baseline (199.471 us; speedup 1.0000x reference)
//
#include <hip/hip_runtime.h>

#define B_    4
#define S_    4096
#define DM    4096
#define DF    256
#define LNEPS 1e-5f

// ws layout: feats_n [B_*DF floats], then meta [8 ints]: meta[2b]=applies, meta[2b+1]=mask count

// Prep: blocks 0..3 -> LayerNorm for batch b; blocks 4..67 -> token/mask scan
// (16 blocks per batch, 256 tokens per block, deterministic int atomics).
__global__ void fvg_prep(const float* __restrict__ ff,
                         const int* __restrict__ toks,
                         const int* __restrict__ attn,
                         const float* __restrict__ gamma,
                         const float* __restrict__ beta,
                         float* __restrict__ feats_n,
                         int* __restrict__ meta) {
    const int blk = blockIdx.x;
    const int t   = threadIdx.x;
    __shared__ float fred[256];

    if (blk < B_) {
        const int b = blk;
        float v = ff[b * DF + t];
        // mean
        fred[t] = v;
        __syncthreads();
        for (int off = 128; off > 0; off >>= 1) {
            if (t < off) fred[t] += fred[t + off];
            __syncthreads();
        }
        float mu = fred[0] * (1.0f / DF);
        __syncthreads();
        // variance
        float d = v - mu;
        fred[t] = d * d;
        __syncthreads();
        for (int off = 128; off > 0; off >>= 1) {
            if (t < off) fred[t] += fred[t + off];
            __syncthreads();
        }
        float rstd = rsqrtf(fred[0] * (1.0f / DF) + LNEPS);
        feats_n[b * DF + t] = d * rstd * gamma[t] + beta[t];
    } else {
        const int j     = blk - B_;     // 0..63
        const int b     = j >> 4;       // 16 blocks per batch
        const int chunk = j & 15;
        const int idx   = b * S_ + chunk * 256 + t;
        int tok = toks[idx];
        int app = (tok == 5) | (tok == 7);
        int cnt = attn[idx];
        #pragma unroll
        for (int m = 32; m >= 1; m >>= 1) {
            app |= __shfl_xor(app, m, 64);
            cnt += __shfl_xor(cnt, m, 64);
        }
        if ((t & 63) == 0) {
            if (app) atomicOr(&meta[b * 2 + 0], 1);
            atomicAdd(&meta[b * 2 + 1], cnt);
        }
    }
}

// Fused copy + inline GEMV + add.
// Grid-stride float4 copy of x->out. A wave covers 256 consecutive floats of
// one row; iterations landing on row (b, last[b]) with applies[b] compute
// delta[d0..d0+3] = dot(feats_n[b,:], W[d,:]) + bias[d] inline and add it.
__global__ void fvg_copy_fused(const float4* __restrict__ x,
                               float4* __restrict__ out,
                               const float* __restrict__ W,
                               const float* __restrict__ bias,
                               const float* __restrict__ feats_n,
                               const int* __restrict__ meta,
                               long n4) {
    // Pack per-batch global target row (b*S_+last) into 16-bit fields;
    // 0xFFFF sentinel when the batch doesn't apply (rows go to 16383 only).
    unsigned long long tp = 0;
    #pragma unroll
    for (int b = 0; b < B_; ++b) {
        int app  = meta[b * 2 + 0];
        int c    = meta[b * 2 + 1];
        int last = (c < 1 ? 1 : c) - 1;
        int tr   = app ? (b * S_ + last) : 0xFFFF;
        tp |= (unsigned long long)(unsigned)tr << (16 * b);
    }

    long i      = (long)blockIdx.x * blockDim.x + threadIdx.x;
    long stride = (long)gridDim.x * blockDim.x;
    for (; i < n4; i += stride) {
        float4 v = x[i];
        int row = (int)(i >> 10);                 // 1024 float4 per row
        int b   = row >> 12;                      // 4096 rows per batch
        int tr  = (int)((tp >> (b * 16)) & 0xFFFFu);
        if (row == tr) {
            int d0 = ((int)(i & 1023)) << 2;      // column of v.x
            const float4* fn = (const float4*)(feats_n + b * DF);
            const float4* w0 = (const float4*)(W + (size_t)(d0 + 0) * DF);
            const float4* w1 = (const float4*)(W + (size_t)(d0 + 1) * DF);
            const float4* w2 = (const float4*)(W + (size_t)(d0 + 2) * DF);
            const float4* w3 = (const float4*)(W + (size_t)(d0 + 3) * DF);
            float a0 = 0.f, a1 = 0.f, a2 = 0.f, a3 = 0.f;
            #pragma unroll 4
            for (int j = 0; j < DF / 4; ++j) {
                float4 f  = fn[j];
                float4 r0 = w0[j], r1 = w1[j], r2 = w2[j], r3 = w3[j];
                a0 += r0.x * f.x + r0.y * f.y + r0.z * f.z + r0.w * f.w;
                a1 += r1.x * f.x + r1.y * f.y + r1.z * f.z + r1.w * f.w;
                a2 += r2.x * f.x + r2.y * f.y + r2.z * f.z + r2.w * f.w;
                a3 += r3.x * f.x + r3.y * f.y + r3.z * f.z + r3.w * f.w;
            }
            float4 bb = *(const float4*)(bias + d0);
            v.x += a0 + bb.x;
            v.y += a1 + bb.y;
            v.z += a2 + bb.z;
            v.w += a3 + bb.w;
        }
        out[i] = v;
    }
}

extern "C" void kernel_launch(void* const* d_in, const int* in_sizes, int n_in,
                              void* d_out, int out_size, void* d_ws, size_t ws_size,
                              hipStream_t stream) {
    const float* x     = (const float*)d_in[0];
    const float* ff    = (const float*)d_in[1];
    const int*   toks  = (const int*)d_in[2];
    const int*   attn  = (const int*)d_in[3];
    const float* gamma = (const float*)d_in[4];
    const float* beta  = (const float*)d_in[5];
    const float* W     = (const float*)d_in[6];
    const float* bias  = (const float*)d_in[7];
    float* out = (float*)d_out;

    float* feats_n = (float*)d_ws;
    int*   meta    = (int*)(feats_n + B_ * DF);

    hipMemsetAsync(meta, 0, 2 * B_ * sizeof(int), stream);
    fvg_prep<<<B_ + 64, 256, 0, stream>>>(ff, toks, attn, gamma, beta, feats_n, meta);

    long n4 = (long)out_size / 4;
    fvg_copy_fused<<<2048, 256, 0, stream>>>((const float4*)x, (float4*)out,
                                             W, bias, feats_n, meta, n4);
}

// Round 3
// 108.271 us; speedup vs baseline: 1.8423x; 1.8423x over previous
//
#include <hip/hip_runtime.h>

#define B_    4
#define S_    4096
#define DM    4096
#define DF    256
#define LNEPS 1e-5f

#define SCAN_BLOCKS  16    // 4 per batch, 1024 tokens each
#define DELTA_BLOCKS 4096  // 4 waves/block, wave per (b,d)
#define COPY_BLOCKS  2048

typedef float f32x4 __attribute__((ext_vector_type(4)));

// ws layout: int app_part[16]; int cnt_part[16]; float delta[B_*DM]

__global__ void fvg_mega(const f32x4* __restrict__ x,
                         f32x4* __restrict__ out,
                         const float* __restrict__ ff,
                         const int* __restrict__ toks,
                         const int* __restrict__ attn,
                         const float* __restrict__ gamma,
                         const float* __restrict__ beta,
                         const float* __restrict__ W,
                         const float* __restrict__ bias,
                         int* __restrict__ app_part,
                         int* __restrict__ cnt_part,
                         float* __restrict__ delta,
                         long n4) {
    const int blk  = blockIdx.x;
    const int t    = threadIdx.x;
    const int lane = t & 63;
    const int wv   = t >> 6;

    if (blk >= SCAN_BLOCKS + DELTA_BLOCKS) {
        // ---- pure streaming copy: branch-free hot loop ----
        long i      = (long)(blk - SCAN_BLOCKS - DELTA_BLOCKS) * 256 + t;
        long stride = (long)COPY_BLOCKS * 256;
        for (; i < n4; i += stride) {
            f32x4 v = __builtin_nontemporal_load(&x[i]);
            __builtin_nontemporal_store(v, &out[i]);
        }
    } else if (blk >= SCAN_BLOCKS) {
        // ---- delta GEMV, wave per (b,d), LayerNorm in-wave ----
        int gw = (blk - SCAN_BLOCKS) * 4 + wv;   // 0 .. B_*DM-1
        int b  = gw >> 12;
        int d  = gw & (DM - 1);

        f32x4 f = ((const f32x4*)(ff + b * DF))[lane];
        float s = f.x + f.y + f.z + f.w;
        #pragma unroll
        for (int m = 32; m >= 1; m >>= 1) s += __shfl_xor(s, m, 64);
        float mu = s * (1.0f / DF);

        f32x4 dv = {f.x - mu, f.y - mu, f.z - mu, f.w - mu};
        float q = dv.x * dv.x + dv.y * dv.y + dv.z * dv.z + dv.w * dv.w;
        #pragma unroll
        for (int m = 32; m >= 1; m >>= 1) q += __shfl_xor(q, m, 64);
        float rstd = rsqrtf(q * (1.0f / DF) + LNEPS);

        f32x4 g  = ((const f32x4*)gamma)[lane];
        f32x4 bt = ((const f32x4*)beta)[lane];
        f32x4 fn = {dv.x * rstd * g.x + bt.x,
                    dv.y * rstd * g.y + bt.y,
                    dv.z * rstd * g.z + bt.z,
                    dv.w * rstd * g.w + bt.w};

        f32x4 w = ((const f32x4*)(W + (size_t)d * DF))[lane];
        float p = fn.x * w.x + fn.y * w.y + fn.z * w.z + fn.w * w.w;
        #pragma unroll
        for (int m = 32; m >= 1; m >>= 1) p += __shfl_xor(p, m, 64);

        if (lane == 0) delta[gw] = p + bias[d];  // 'applies' scaling done in add
    } else {
        // ---- token/mask scan partials: block covers 1024 tokens ----
        __shared__ int s_app[4], s_cnt[4];
        const int b     = blk >> 2;
        const int chunk = blk & 3;
        const int4* tp = (const int4*)(toks + b * S_ + chunk * 1024);
        const int4* ap = (const int4*)(attn + b * S_ + chunk * 1024);
        int4 tv = tp[t];
        int4 av = ap[t];
        int app = (tv.x == 5) | (tv.x == 7) | (tv.y == 5) | (tv.y == 7) |
                  (tv.z == 5) | (tv.z == 7) | (tv.w == 5) | (tv.w == 7);
        int cnt = av.x + av.y + av.z + av.w;
        #pragma unroll
        for (int m = 32; m >= 1; m >>= 1) {
            app |= __shfl_xor(app, m, 64);
            cnt += __shfl_xor(cnt, m, 64);
        }
        if (lane == 0) { s_app[wv] = app; s_cnt[wv] = cnt; }
        __syncthreads();
        if (t == 0) {
            app_part[blk] = s_app[0] | s_app[1] | s_app[2] | s_app[3];
            cnt_part[blk] = s_cnt[0] + s_cnt[1] + s_cnt[2] + s_cnt[3];
        }
    }
}

// out[b, last[b], :] += delta[b,:] * applies[b]
__global__ void fvg_add(float* __restrict__ out,
                        const float* __restrict__ delta,
                        const int* __restrict__ app_part,
                        const int* __restrict__ cnt_part) {
    int i = blockIdx.x * 256 + threadIdx.x;  // 0 .. B_*DM-1
    int b = i >> 12;
    int d = i & (DM - 1);
    int app = app_part[b * 4 + 0] | app_part[b * 4 + 1] |
              app_part[b * 4 + 2] | app_part[b * 4 + 3];
    int cnt = cnt_part[b * 4 + 0] + cnt_part[b * 4 + 1] +
              cnt_part[b * 4 + 2] + cnt_part[b * 4 + 3];
    int last = (cnt < 1 ? 1 : cnt) - 1;
    if (app) {
        size_t off = ((size_t)b * S_ + (size_t)last) * DM + d;
        out[off] += delta[i];
    }
}

extern "C" void kernel_launch(void* const* d_in, const int* in_sizes, int n_in,
                              void* d_out, int out_size, void* d_ws, size_t ws_size,
                              hipStream_t stream) {
    const float* x     = (const float*)d_in[0];
    const float* ff    = (const float*)d_in[1];
    const int*   toks  = (const int*)d_in[2];
    const int*   attn  = (const int*)d_in[3];
    const float* gamma = (const float*)d_in[4];
    const float* beta  = (const float*)d_in[5];
    const float* W     = (const float*)d_in[6];
    const float* bias  = (const float*)d_in[7];
    float* out = (float*)d_out;

    int*   app_part = (int*)d_ws;
    int*   cnt_part = app_part + SCAN_BLOCKS;
    float* delta    = (float*)(cnt_part + SCAN_BLOCKS);

    long n4 = (long)out_size / 4;

    fvg_mega<<<SCAN_BLOCKS + DELTA_BLOCKS + COPY_BLOCKS, 256, 0, stream>>>(
        (const f32x4*)x, (f32x4*)out, ff, toks, attn, gamma, beta, W, bias,
        app_part, cnt_part, delta, n4);

    fvg_add<<<(B_ * DM) / 256, 256, 0, stream>>>(out, delta, app_part, cnt_part);
}

// Round 4
// 101.574 us; speedup vs baseline: 1.9638x; 1.0659x over previous
//
#include <hip/hip_runtime.h>

#define B_    4
#define S_    4096
#define DM    4096
#define DF    256
#define LNEPS 1e-5f

#define COPY_BLOCKS  2048
#define SCAN_BLOCKS  16    // 4 per batch, 1024 tokens each
#define DELTA_BLOCKS 256   // 4 waves/block, each wave does 16 d-rows

typedef float f32x4 __attribute__((ext_vector_type(4)));

// ws layout: int app_part[16]; int cnt_part[16]; float delta[B_*DM]

__global__ void fvg_mega(const f32x4* __restrict__ x,
                         f32x4* __restrict__ out,
                         const float* __restrict__ ff,
                         const int* __restrict__ toks,
                         const int* __restrict__ attn,
                         const float* __restrict__ gamma,
                         const float* __restrict__ beta,
                         const float* __restrict__ W,
                         const float* __restrict__ bias,
                         int* __restrict__ app_part,
                         int* __restrict__ cnt_part,
                         float* __restrict__ delta,
                         long n4) {
    const int blk  = blockIdx.x;
    const int t    = threadIdx.x;
    const int lane = t & 63;
    const int wv   = t >> 6;

    if (blk < COPY_BLOCKS) {
        // ---- pure streaming copy: branch-free hot loop, starts immediately ----
        long i      = (long)blk * 256 + t;
        long stride = (long)COPY_BLOCKS * 256;
        for (; i < n4; i += stride) {
            f32x4 v = __builtin_nontemporal_load(&x[i]);
            __builtin_nontemporal_store(v, &out[i]);
        }
    } else if (blk < COPY_BLOCKS + SCAN_BLOCKS) {
        // ---- token/mask scan partials: block covers 1024 tokens ----
        __shared__ int s_app[4], s_cnt[4];
        const int j     = blk - COPY_BLOCKS;
        const int b     = j >> 2;
        const int chunk = j & 3;
        const int4* tp = (const int4*)(toks + b * S_ + chunk * 1024);
        const int4* ap = (const int4*)(attn + b * S_ + chunk * 1024);
        int4 tv = tp[t];
        int4 av = ap[t];
        int app = (tv.x == 5) | (tv.x == 7) | (tv.y == 5) | (tv.y == 7) |
                  (tv.z == 5) | (tv.z == 7) | (tv.w == 5) | (tv.w == 7);
        int cnt = av.x + av.y + av.z + av.w;
        #pragma unroll
        for (int m = 32; m >= 1; m >>= 1) {
            app |= __shfl_xor(app, m, 64);
            cnt += __shfl_xor(cnt, m, 64);
        }
        if (lane == 0) { s_app[wv] = app; s_cnt[wv] = cnt; }
        __syncthreads();
        if (t == 0) {
            app_part[j] = s_app[0] | s_app[1] | s_app[2] | s_app[3];
            cnt_part[j] = s_cnt[0] + s_cnt[1] + s_cnt[2] + s_cnt[3];
        }
    } else {
        // ---- delta GEMV: 1024 waves, each does LN once + 16 d-rows ----
        int gw    = (blk - COPY_BLOCKS - SCAN_BLOCKS) * 4 + wv;  // 0..1023
        int b     = gw >> 8;              // 256 waves per batch
        int dbase = (gw & 255) * 16;

        f32x4 f = ((const f32x4*)(ff + b * DF))[lane];
        float s = f.x + f.y + f.z + f.w;
        #pragma unroll
        for (int m = 32; m >= 1; m >>= 1) s += __shfl_xor(s, m, 64);
        float mu = s * (1.0f / DF);

        f32x4 dv = {f.x - mu, f.y - mu, f.z - mu, f.w - mu};
        float q = dv.x * dv.x + dv.y * dv.y + dv.z * dv.z + dv.w * dv.w;
        #pragma unroll
        for (int m = 32; m >= 1; m >>= 1) q += __shfl_xor(q, m, 64);
        float rstd = rsqrtf(q * (1.0f / DF) + LNEPS);

        f32x4 g  = ((const f32x4*)gamma)[lane];
        f32x4 bt = ((const f32x4*)beta)[lane];
        f32x4 fn = {dv.x * rstd * g.x + bt.x,
                    dv.y * rstd * g.y + bt.y,
                    dv.z * rstd * g.z + bt.z,
                    dv.w * rstd * g.w + bt.w};

        // 16 rows: issue all loads + partial dots, then interleaved reductions
        float p[16];
        #pragma unroll
        for (int r = 0; r < 16; ++r) {
            f32x4 w = ((const f32x4*)(W + (size_t)(dbase + r) * DF))[lane];
            p[r] = fn.x * w.x + fn.y * w.y + fn.z * w.z + fn.w * w.w;
        }
        #pragma unroll
        for (int m = 32; m >= 1; m >>= 1) {
            #pragma unroll
            for (int r = 0; r < 16; ++r) p[r] += __shfl_xor(p[r], m, 64);
        }
        if (lane == 0) {
            #pragma unroll
            for (int r = 0; r < 16; ++r)
                delta[b * DM + dbase + r] = p[r] + bias[dbase + r];
        }
    }
}

// out[b, last[b], :] += delta[b,:] * applies[b]
__global__ void fvg_add(float* __restrict__ out,
                        const float* __restrict__ delta,
                        const int* __restrict__ app_part,
                        const int* __restrict__ cnt_part) {
    int i = blockIdx.x * 256 + threadIdx.x;  // 0 .. B_*DM-1
    int b = i >> 12;
    int d = i & (DM - 1);
    int app = app_part[b * 4 + 0] | app_part[b * 4 + 1] |
              app_part[b * 4 + 2] | app_part[b * 4 + 3];
    int cnt = cnt_part[b * 4 + 0] + cnt_part[b * 4 + 1] +
              cnt_part[b * 4 + 2] + cnt_part[b * 4 + 3];
    int last = (cnt < 1 ? 1 : cnt) - 1;
    if (app) {
        size_t off = ((size_t)b * S_ + (size_t)last) * DM + d;
        out[off] += delta[i];
    }
}

extern "C" void kernel_launch(void* const* d_in, const int* in_sizes, int n_in,
                              void* d_out, int out_size, void* d_ws, size_t ws_size,
                              hipStream_t stream) {
    const float* x     = (const float*)d_in[0];
    const float* ff    = (const float*)d_in[1];
    const int*   toks  = (const int*)d_in[2];
    const int*   attn  = (const int*)d_in[3];
    const float* gamma = (const float*)d_in[4];
    const float* beta  = (const float*)d_in[5];
    const float* W     = (const float*)d_in[6];
    const float* bias  = (const float*)d_in[7];
    float* out = (float*)d_out;

    int*   app_part = (int*)d_ws;
    int*   cnt_part = app_part + SCAN_BLOCKS;
    float* delta    = (float*)(cnt_part + SCAN_BLOCKS);

    long n4 = (long)out_size / 4;

    fvg_mega<<<COPY_BLOCKS + SCAN_BLOCKS + DELTA_BLOCKS, 256, 0, stream>>>(
        (const f32x4*)x, (f32x4*)out, ff, toks, attn, gamma, beta, W, bias,
        app_part, cnt_part, delta, n4);

    fvg_add<<<(B_ * DM) / 256, 256, 0, stream>>>(out, delta, app_part, cnt_part);
}